// Round 20
// baseline (489.014 us; speedup 1.0000x reference)
//
#include <hip/hip_runtime.h>
#include <hip/hip_bf16.h>
#include <stdint.h>

// ---------------- static problem sizes ----------------
#define BB    32
#define NPER  1024
#define NTOT  32768
#define DD    128
#define HH    4
#define HD    32
#define LL    3
#define DFF   2048
#define INDIM 64
// 1/sqrt(32) * log2(e): Q pre-scale folds the base-2 conversion so the
// softmax exp is a bare v_exp_f32 (saves one v_mul per element).
#define QKSCALE_L2E 0.2550348635f

typedef unsigned short u16;
typedef short bf16x8 __attribute__((ext_vector_type(8)));   // 8 bf16 (4 VGPRs)
typedef float f32x4 __attribute__((ext_vector_type(4)));

// address-space casts for global_load_lds (direct global->LDS DMA)
#define AS_GLOBAL(p) ((const __attribute__((address_space(1))) void*)(p))
#define AS_LDS(p)    ((__attribute__((address_space(3))) void*)(p))

__device__ __forceinline__ float bf2f(u16 v){
  unsigned u = ((unsigned)v) << 16; float f; __builtin_memcpy(&f, &u, 4); return f;
}
__device__ __forceinline__ u16 f2bf(float f){
  unsigned u; __builtin_memcpy(&u, &f, 4);
  unsigned lsb = (u >> 16) & 1u;
  u += 0x7fffu + lsb;              // round-to-nearest-even
  return (u16)(u >> 16);
}
// pack two f32 -> two bf16 by truncation (3 ops; P-values only: <=0.2% bias)
__device__ __forceinline__ unsigned pk_bf_trunc(float a, float b){
  unsigned ua, ub;
  __builtin_memcpy(&ua, &a, 4); __builtin_memcpy(&ub, &b, 4);
  return (ub & 0xFFFF0000u) | (ua >> 16);
}

// ---------------- workspace layout (bytes) ----------------
constexpr size_t OFF_FLAG   = 0;
constexpr size_t OFF_STARTS = 256;
constexpr size_t OFF_BIN    = 1024;
constexpr size_t OFF_BQKV   = OFF_BIN   + 128*4;
constexpr size_t OFF_BO     = OFF_BQKV  + 1152*4;
constexpr size_t OFF_B1     = OFF_BO    + 384*4;
constexpr size_t OFF_B2     = OFF_B1    + 6144*4;
constexpr size_t OFF_LN1G   = OFF_B2    + 384*4;
constexpr size_t OFF_LN1B   = OFF_LN1G  + 384*4;
constexpr size_t OFF_LN2G   = OFF_LN1B  + 384*4;
constexpr size_t OFF_LN2B   = OFF_LN2G  + 384*4;
constexpr size_t OFF_XB     = 40960;                               // (unused)
constexpr size_t OFF_WINB   = OFF_XB    + (size_t)2097152*2;
constexpr size_t OFF_WQKVB  = OFF_WINB  + (size_t)8192*2;
constexpr size_t OFF_WOB    = OFF_WQKVB + (size_t)147456*2;
constexpr size_t OFF_W1B    = OFF_WOB   + (size_t)49152*2;
constexpr size_t OFF_W2B    = OFF_W1B   + (size_t)786432*2;
constexpr size_t OFF_CUR    = OFF_W2B   + (size_t)786432*2;
constexpr size_t OFF_TMP    = OFF_CUR   + (size_t)4194304*4;      // (unused)
constexpr size_t OFF_CURB   = OFF_TMP   + (size_t)4194304*4;
constexpr size_t OFF_QKVB   = OFF_CURB  + (size_t)4194304*2;      // QH (8 MB) + KT (8 MB)
constexpr size_t OFF_ATTNOB = OFF_QKVB  + (size_t)12582912*2;
constexpr size_t OFF_ACTB   = OFF_ATTNOB+ (size_t)4194304*2;      // (unused)
constexpr size_t OFF_MASK   = OFF_ACTB  + (size_t)16777216*2;
constexpr size_t OFF_VT     = OFF_MASK  + (size_t)NTOT*4;         // VTile (8 MB)
constexpr size_t OFF_RED    = OFF_VT    + (size_t)4096*1024*2;
constexpr size_t OFF_CNT    = OFF_RED   + (size_t)32*8*128*4;

// ---------------- dtype detection + graph starts (one launch) ----------------
__device__ __forceinline__ int plaus(unsigned bits){
  if ((bits << 1) == 0u) return 1;
  unsigned e = (bits >> 23) & 0xFFu;
  return (e >= 100u && e <= 140u) ? 1 : 0;
}
__global__ void prep_kernel(const unsigned* __restrict__ x, const int* __restrict__ batch,
                            int* __restrict__ flag, int* __restrict__ starts){
  __shared__ int red[256];
  int t = threadIdx.x, c = 0;
  for (int i = t; i < 2048; i += 256){
    unsigned w = x[i];
    c += (plaus(w << 16) & plaus(w & 0xFFFF0000u));
  }
  red[t] = c; __syncthreads();
  for (int s = 128; s > 0; s >>= 1){ if (t < s) red[t] += red[t+s]; __syncthreads(); }
  if (t == 0) *flag = (red[0] >= 1229) ? 1 : 0;
  if (t < BB){
    int lo = 0, hi = NTOT;
    while (lo < hi){ int mid = (lo + hi) >> 1; if (batch[mid] < t) lo = mid + 1; else hi = mid; }
    starts[t] = lo;
  }
}

// ---------------- fused conversion of weight/bias tensors (1 launch) ----------------
struct ConvSeg { const void* src; void* dst; int n; int tobf; };
struct ConvArgs { ConvSeg s[14]; };

__global__ __launch_bounds__(256) void convall_kernel(ConvArgs a, const int* __restrict__ flag){
  const int isb = *flag;
  const int blk = blockIdx.x;
  int seg = -1, base = 0, lb = 0;
  #pragma unroll
  for (int i = 0; i < 14; ++i){
    int nb = (a.s[i].n + 1023) >> 10;
    if (seg < 0){
      if (blk < base + nb){ seg = i; lb = blk - base; }
      base += nb;
    }
  }
  const ConvSeg sg = a.s[seg];
  const int idx = lb*1024 + threadIdx.x*4;
  if (idx >= sg.n) return;
  if (sg.tobf){
    u16* dst = (u16*)sg.dst + idx;
    if (isb){
      *(uint2*)dst = *(const uint2*)((const u16*)sg.src + idx);
    } else {
      const float* s4 = (const float*)sg.src + idx;
      dst[0] = f2bf(s4[0]); dst[1] = f2bf(s4[1]);
      dst[2] = f2bf(s4[2]); dst[3] = f2bf(s4[3]);
    }
  } else {
    float* dst = (float*)sg.dst + idx;
    if (isb){
      const u16* s4 = (const u16*)sg.src + idx;
      dst[0] = bf2f(s4[0]); dst[1] = bf2f(s4[1]);
      dst[2] = bf2f(s4[2]); dst[3] = bf2f(s4[3]);
    } else {
      *(float4*)dst = *(const float4*)((const float*)sg.src + idx);
    }
  }
}

// ---------------- fused input projection + scatter + mask (dual-dtype x) ----------------
__global__ __launch_bounds__(256) void inproj_kernel(
    const void* __restrict__ xraw,    // [NTOT][64] bf16 or f32 (per flag)
    const u16* __restrict__ WINB,     // [128][64] bf16
    const float* __restrict__ bin,    // [128]
    const int* __restrict__ batch, const int* __restrict__ starts,
    const int* __restrict__ flag,
    float* __restrict__ cur, u16* __restrict__ curb, float* __restrict__ mask)
{
  __shared__ __align__(16) u16 Wl[8192];           // 128 rows x 64 k, XOR8 swizzle
  const int t = threadIdx.x, wave = t >> 6, lane = t & 63;
  const int quad = lane >> 4, l16 = lane & 15;
  const int m0 = blockIdx.x * 64;
  const int isb = *flag;

  #pragma unroll
  for (int j = 0; j < 4; ++j){
    int s = t + 256*j;
    int r = s >> 3, c8 = (s & 7) ^ (r & 7);
    *(uint4*)&Wl[s*8] = *(const uint4*)(WINB + (size_t)r*INDIM + c8*8);
  }
  bf16x8 af[2];
  const int arow = m0 + wave*16 + l16;
  if (isb){
    const u16* XB = (const u16*)xraw;
    #pragma unroll
    for (int kk = 0; kk < 2; ++kk)
      af[kk] = *(const bf16x8*)(XB + (size_t)arow*INDIM + kk*32 + quad*8);
  } else {
    const float* Xf = (const float*)xraw;
    #pragma unroll
    for (int kk = 0; kk < 2; ++kk){
      float4 a = *(const float4*)(Xf + (size_t)arow*INDIM + kk*32 + quad*8);
      float4 b = *(const float4*)(Xf + (size_t)arow*INDIM + kk*32 + quad*8 + 4);
      af[kk][0] = (short)f2bf(a.x); af[kk][1] = (short)f2bf(a.y);
      af[kk][2] = (short)f2bf(a.z); af[kk][3] = (short)f2bf(a.w);
      af[kk][4] = (short)f2bf(b.x); af[kk][5] = (short)f2bf(b.y);
      af[kk][6] = (short)f2bf(b.z); af[kk][7] = (short)f2bf(b.w);
    }
  }
  __syncthreads();

  f32x4 O[8];
  #pragma unroll
  for (int nt = 0; nt < 8; ++nt){ O[nt][0]=0.f; O[nt][1]=0.f; O[nt][2]=0.f; O[nt][3]=0.f; }

  #pragma unroll
  for (int nt = 0; nt < 8; ++nt){
    int row = nt*16 + l16;
    bf16x8 wf[2];
    #pragma unroll
    for (int kk = 0; kk < 2; ++kk)
      wf[kk] = *(const bf16x8*)&Wl[(row*8 + ((kk*4 + quad) ^ (row & 7)))*8];
    #pragma unroll
    for (int kk = 0; kk < 2; ++kk)
      O[nt] = __builtin_amdgcn_mfma_f32_16x16x32_bf16(af[kk], wf[kk], O[nt], 0, 0, 0);
  }

  #pragma unroll
  for (int rr = 0; rr < 4; ++rr){
    int node = m0 + wave*16 + quad*4 + rr;
    int gr = batch[node];
    int p  = node - starts[gr];
    float vs[8], sum = 0.f;
    #pragma unroll
    for (int nt = 0; nt < 8; ++nt){
      float v = O[nt][rr] + bin[nt*16 + l16];
      vs[nt] = v; sum += v;
    }
    sum += __shfl_xor(sum, 1); sum += __shfl_xor(sum, 2);
    sum += __shfl_xor(sum, 4); sum += __shfl_xor(sum, 8);
    if ((unsigned)p < (unsigned)NPER && (unsigned)gr < (unsigned)BB){
      size_t j = (size_t)gr*NPER + p;
      #pragma unroll
      for (int nt = 0; nt < 8; ++nt){
        int col = nt*16 + l16;
        cur[j*DD + col]  = vs[nt];
        curb[j*DD + col] = f2bf(vs[nt]);
      }
      if (l16 == 0) mask[j] = (sum != 0.f) ? 1.f : 0.f;
    }
  }
}

// ---------------- MFMA flash attention v7: exp2-folded scale ----------------
__global__ __launch_bounds__(256) void fattn_kernel(
    const u16* __restrict__ qh,     // [BH][NPER][32]
    const u16* __restrict__ ktb,    // [BH][NPER*32] tiled
    const u16* __restrict__ vtb,    // [BH][NPER*32] tiled
    u16* __restrict__ attnob)       // [NTOT][128]
{
  __shared__ __align__(16) u16 Klds[2][2048];      // [c(4)][r(64)][8]
  __shared__ __align__(16) u16 Vl[2][2048];        // [cv(8)][d(32)][8]
  __shared__ __align__(16) u16 Pl[4][2][16*72];    // per-(wave,qt) P [q][s], pitch 72

  const int t = threadIdx.x;
  const int wave = t >> 6, lane = t & 63;
  const int quad = lane >> 4, l16 = lane & 15;
  const int q0 = blockIdx.x * 128;
  const int h = blockIdx.y, b = blockIdx.z;
  const size_t bh = (size_t)(b*HH + h) * NPER * 32;
  const u16* Qg = qh + bh;
  const u16* Kg = ktb + bh;
  const u16* Vg = vtb + bh;

  bf16x8 qf[2];
  #pragma unroll
  for (int qt = 0; qt < 2; ++qt){
    uint4 qv = *(const uint4*)(Qg + (size_t)(q0 + wave*32 + qt*16 + l16)*32 + quad*8);
    u16 raw[8]; __builtin_memcpy(raw, &qv, 16);
    #pragma unroll
    for (int j = 0; j < 8; ++j) qf[qt][j] = (short)f2bf(bf2f(raw[j]) * QKSCALE_L2E);
  }

  auto stage = [&](int buf, int kt){
    __builtin_amdgcn_global_load_lds(
        AS_GLOBAL(Kg + kt*2048 + wave*512 + lane*8),
        AS_LDS(&Klds[buf][wave*64*8]), 16, 0, 0);
    __builtin_amdgcn_global_load_lds(
        AS_GLOBAL(Vg + kt*2048 + wave*512 + lane*8),
        AS_LDS(&Vl[buf][wave*64*8]), 16, 0, 0);
  };

  float lsum[2] = {0.f, 0.f};
  f32x4 o[2][2];
  #pragma unroll
  for (int qt = 0; qt < 2; ++qt)
    #pragma unroll
    for (int i = 0; i < 2; ++i){ o[qt][i][0]=0.f; o[qt][i][1]=0.f; o[qt][i][2]=0.f; o[qt][i][3]=0.f; }

  stage(0, 0);
  asm volatile("s_waitcnt vmcnt(0)" ::: "memory");
  __syncthreads();

  for (int kt = 0; kt < 16; ++kt){
    const int buf = kt & 1;
    if (kt + 1 < 16) stage(buf ^ 1, kt + 1);

    f32x4 sfr[2][4];
    #pragma unroll
    for (int nt = 0; nt < 4; ++nt){
      bf16x8 kf = *(const bf16x8*)&Klds[buf][(quad*64 + nt*16 + l16)*8];
      f32x4 z = {0.f,0.f,0.f,0.f};
      sfr[0][nt] = __builtin_amdgcn_mfma_f32_16x16x32_bf16(kf, qf[0], z, 0, 0, 0);
      sfr[1][nt] = __builtin_amdgcn_mfma_f32_16x16x32_bf16(kf, qf[1], z, 0, 0, 0);
    }

    #pragma unroll
    for (int qt = 0; qt < 2; ++qt){
      float ps = 0.f;
      #pragma unroll
      for (int nt = 0; nt < 4; ++nt){
        float e0 = exp2f(sfr[qt][nt][0]), e1 = exp2f(sfr[qt][nt][1]);
        float e2 = exp2f(sfr[qt][nt][2]), e3 = exp2f(sfr[qt][nt][3]);
        ps += (e0 + e1) + (e2 + e3);
        uint2 w;
        w.x = pk_bf_trunc(e0, e1);
        w.y = pk_bf_trunc(e2, e3);
        *(uint2*)&Pl[wave][qt][l16*72 + nt*16 + quad*4] = w;
      }
      ps += __shfl_xor(ps, 16);
      ps += __shfl_xor(ps, 32);
      lsum[qt] += ps;
    }
    asm volatile("s_waitcnt lgkmcnt(0)" ::: "memory");

    #pragma unroll
    for (int kk = 0; kk < 2; ++kk){
      bf16x8 v0 = *(const bf16x8*)&Vl[buf][((kk*4 + quad)*32 + l16)*8];
      bf16x8 v1 = *(const bf16x8*)&Vl[buf][((kk*4 + quad)*32 + 16 + l16)*8];
      #pragma unroll
      for (int qt = 0; qt < 2; ++qt){
        bf16x8 pf = *(const bf16x8*)&Pl[wave][qt][l16*72 + kk*32 + quad*8];
        o[qt][0] = __builtin_amdgcn_mfma_f32_16x16x32_bf16(pf, v0, o[qt][0], 0, 0, 0);
        o[qt][1] = __builtin_amdgcn_mfma_f32_16x16x32_bf16(pf, v1, o[qt][1], 0, 0, 0);
      }
    }

    if (kt + 1 < 16){
      asm volatile("s_waitcnt vmcnt(0)" ::: "memory");
      __syncthreads();
    }
  }

  #pragma unroll
  for (int qt = 0; qt < 2; ++qt){
    #pragma unroll
    for (int r = 0; r < 4; ++r){
      float inv = 1.f / __shfl(lsum[qt], quad*4 + r);
      int row = q0 + wave*32 + qt*16 + quad*4 + r;
      size_t base = (size_t)(b*NPER + row)*DD + h*HD;
      attnob[base + l16]      = f2bf(o[qt][0][r] * inv);
      attnob[base + 16 + l16] = f2bf(o[qt][1][r] * inv);
    }
  }
}

// ---------------- QKV GEMM: 128-row blocks, wave owns 32 rows, head-major out ----------------
__global__ __launch_bounds__(256) void wgemm2_kernel(
    const u16* __restrict__ A,        // [M][128] bf16
    const u16* __restrict__ Wbase,    // [3*128][128] bf16
    const float* __restrict__ biasb,  // [3*128]
    u16* __restrict__ qh, u16* __restrict__ ktb, u16* __restrict__ vtb)
{
  __shared__ __align__(16) u16 Wl[16384];          // 128x128, XOR-swizzled chunks
  const int t = threadIdx.x, wave = t >> 6, lane = t & 63;
  const int quad = lane >> 4, l16 = lane & 15;
  const int m0 = blockIdx.x * 128, nb = blockIdx.y;
  const u16* Wsl = Wbase + (size_t)nb * 16384;
  const float* bias = biasb + nb * 128;

  #pragma unroll
  for (int j = 0; j < 8; ++j){
    int s = t + 256*j;
    int r = s >> 4, cx = (s & 15) ^ (r & 15);
    *(uint4*)&Wl[s*8] = *(const uint4*)(Wsl + (size_t)r*128 + cx*8);
  }
  bf16x8 af[2][4];
  #pragma unroll
  for (int mt = 0; mt < 2; ++mt)
    #pragma unroll
    for (int kk = 0; kk < 4; ++kk)
      af[mt][kk] = *(const bf16x8*)(A + (size_t)(m0 + wave*32 + mt*16 + l16)*128 + kk*32 + quad*8);
  __syncthreads();

  f32x4 O[2][8];
  #pragma unroll
  for (int mt = 0; mt < 2; ++mt)
    #pragma unroll
    for (int nt = 0; nt < 8; ++nt){ O[mt][nt][0]=0.f; O[mt][nt][1]=0.f; O[mt][nt][2]=0.f; O[mt][nt][3]=0.f; }

  #pragma unroll
  for (int nt = 0; nt < 8; ++nt){
    int row = nt*16 + l16;
    bf16x8 wf[4];
    #pragma unroll
    for (int kk = 0; kk < 4; ++kk)
      wf[kk] = *(const bf16x8*)&Wl[(row*16 + ((kk*4 + quad) ^ l16))*8];
    #pragma unroll
    for (int mt = 0; mt < 2; ++mt)
      #pragma unroll
      for (int kk = 0; kk < 4; ++kk)
        O[mt][nt] = __builtin_amdgcn_mfma_f32_16x16x32_bf16(af[mt][kk], wf[kk], O[mt][nt], 0, 0, 0);
  }

  if (nb == 0){
    #pragma unroll
    for (int mt = 0; mt < 2; ++mt)
      #pragma unroll
      for (int rr = 0; rr < 4; ++rr){
        int s = m0 + wave*32 + mt*16 + quad*4 + rr;
        int bg = s >> 10, sl = s & 1023;
        #pragma unroll
        for (int nt = 0; nt < 8; ++nt){
          int col = nt*16 + l16, hh = col >> 5, d = col & 31;
          qh[((size_t)(bg*HH + hh)*NPER + sl)*32 + d] = f2bf(O[mt][nt][rr] + bias[col]);
        }
      }
  } else if (nb == 1){
    #pragma unroll
    for (int mt = 0; mt < 2; ++mt)
      #pragma unroll
      for (int rr = 0; rr < 4; ++rr){
        int s = m0 + wave*32 + mt*16 + quad*4 + rr;
        int bg = s >> 10, sl = s & 1023;
        int kt = sl >> 6, r = sl & 63;
        #pragma unroll
        for (int nt = 0; nt < 8; ++nt){
          int col = nt*16 + l16, hh = col >> 5, d = col & 31;
          ktb[(size_t)(bg*HH + hh)*NPER*32 + kt*2048 + (d>>3)*512 + r*8 + (d&7)]
              = f2bf(O[mt][nt][rr] + bias[col]);
        }
      }
  } else {
    #pragma unroll
    for (int mt = 0; mt < 2; ++mt){
      int rowb = m0 + wave*32 + mt*16 + quad*4;
      int bg = rowb >> 10, sl = rowb & 1023;
      int kt = sl >> 6, cv = (sl & 63) >> 3, j0 = sl & 7;
      #pragma unroll
      for (int nt = 0; nt < 8; ++nt){
        int col = nt*16 + l16, hh = col >> 5, d = col & 31;
        float v0 = O[mt][nt][0] + bias[col], v1 = O[mt][nt][1] + bias[col];
        float v2 = O[mt][nt][2] + bias[col], v3 = O[mt][nt][3] + bias[col];
        uint2 w;
        w.x = (unsigned)f2bf(v0) | ((unsigned)f2bf(v1) << 16);
        w.y = (unsigned)f2bf(v2) | ((unsigned)f2bf(v3) << 16);
        *(uint2*)(vtb + (size_t)(bg*HH + hh)*NPER*32 + kt*2048 + cv*256 + d*8 + j0) = w;
      }
    }
  }
}

// ---------------- fused Wo+LN1+FFN+LN2 (R17-measured best: BK=64, 2 blocks/CU) ----------------
__global__ __launch_bounds__(256, 2) void ffn_kernel(
    const u16* __restrict__ attnob,   // [M][128] bf16
    const u16* __restrict__ Wog,      // [128][128] bf16
    const float* __restrict__ bo,
    const float* __restrict__ g1, const float* __restrict__ beta1,
    const u16* __restrict__ W1g,      // [2048][128]
    const u16* __restrict__ W2g,      // [128][2048]
    const float* __restrict__ b1,
    const float* __restrict__ b2,
    const float* __restrict__ g2, const float* __restrict__ beta2,
    float* __restrict__ cur, u16* __restrict__ curb)
{
  // carved LDS: [0,16384) W1l dbuf, [16384,32768) W2l dbuf, [32768,37376) Pl
  __shared__ __align__(16) u16 SM[37376];
  const int t = threadIdx.x, wave = t >> 6, lane = t & 63;
  const int quad = lane >> 4, l16 = lane & 15;
  const int m0 = blockIdx.x * 64;
  u16* Pw = &SM[32768 + wave*1152];

  auto stageW1 = [&](int buf, int dffc){
    #pragma unroll
    for (int i = 0; i < 4; ++i){
      const int s0 = wave*256 + i*64;
      const int s  = s0 + lane;
      int r = s >> 4, cx = (s & 15) ^ (r & 15);
      __builtin_amdgcn_global_load_lds(
          AS_GLOBAL(W1g + (size_t)(dffc + r)*128 + cx*8),
          AS_LDS(&SM[buf*8192 + s0*8]), 16, 0, 0);
    }
  };
  auto stageW2 = [&](int buf, int dffc){
    #pragma unroll
    for (int i = 0; i < 4; ++i){
      const int s0 = wave*256 + i*64;
      const int s  = s0 + lane;
      int r = s >> 3, cx = (s & 7) ^ (r & 7);
      __builtin_amdgcn_global_load_lds(
          AS_GLOBAL(W2g + (size_t)r*DFF + dffc + cx*8),
          AS_LDS(&SM[16384 + buf*8192 + s0*8]), 16, 0, 0);
    }
  };

  // ---- prologue: Wo into W2l region + W1 chunk0 into W1l buf0 (overlapped) ----
  #pragma unroll
  for (int i = 0; i < 8; ++i){
    int s0 = wave*512 + i*64;
    int s = s0 + lane;
    int r = s >> 4, cx = (s & 15) ^ (r & 15);
    __builtin_amdgcn_global_load_lds(
        AS_GLOBAL(Wog + (size_t)r*128 + cx*8),
        AS_LDS(&SM[16384 + s0*8]), 16, 0, 0);
  }
  stageW1(0, 0);                                   // W1l region idle during prologue
  bf16x8 afo[4];
  #pragma unroll
  for (int kk = 0; kk < 4; ++kk)
    afo[kk] = *(const bf16x8*)(attnob + (size_t)(m0 + wave*16 + l16)*128 + kk*32 + quad*8);
  asm volatile("s_waitcnt vmcnt(0)" ::: "memory");
  __syncthreads();

  f32x4 O[8];
  #pragma unroll
  for (int nt = 0; nt < 8; ++nt){ O[nt][0]=0.f; O[nt][1]=0.f; O[nt][2]=0.f; O[nt][3]=0.f; }
  #pragma unroll
  for (int nt = 0; nt < 8; ++nt){
    int row = nt*16 + l16;
    bf16x8 wf[4];
    #pragma unroll
    for (int kk = 0; kk < 4; ++kk)
      wf[kk] = *(const bf16x8*)&SM[16384 + (row*16 + ((kk*4 + quad) ^ l16))*8];
    #pragma unroll
    for (int kk = 0; kk < 4; ++kk)
      O[nt] = __builtin_amdgcn_mfma_f32_16x16x32_bf16(afo[kk], wf[kk], O[nt], 0, 0, 0);
  }

  float res[8][4];
  u16* Tw = &SM[24576 + wave*2048];                // 16 rows x pitch 128, W2l buf1 region
  #pragma unroll
  for (int rr = 0; rr < 4; ++rr){
    int row = m0 + wave*16 + quad*4 + rr;
    float vs[8], sum = 0.f;
    #pragma unroll
    for (int nt = 0; nt < 8; ++nt){
      int col = nt*16 + l16;
      float v = O[nt][rr] + bo[col] + cur[(size_t)row*DD + col];
      vs[nt] = v; sum += v;
    }
    sum += __shfl_xor(sum, 1); sum += __shfl_xor(sum, 2);
    sum += __shfl_xor(sum, 4); sum += __shfl_xor(sum, 8);
    float mean = sum * (1.f/DD);
    float sq = 0.f;
    #pragma unroll
    for (int nt = 0; nt < 8; ++nt){ float d = vs[nt] - mean; sq += d*d; }
    sq += __shfl_xor(sq, 1); sq += __shfl_xor(sq, 2);
    sq += __shfl_xor(sq, 4); sq += __shfl_xor(sq, 8);
    float rs = rsqrtf(sq * (1.f/DD) + 1e-5f);
    #pragma unroll
    for (int nt = 0; nt < 8; ++nt){
      int col = nt*16 + l16;
      float o = (vs[nt] - mean)*rs*g1[col] + beta1[col];
      res[nt][rr] = o;
      Tw[(quad*4 + rr)*128 + col] = f2bf(o);
    }
  }
  asm volatile("s_waitcnt lgkmcnt(0)" ::: "memory");

  bf16x8 af[4];
  #pragma unroll
  for (int kk = 0; kk < 4; ++kk)
    af[kk] = *(const bf16x8*)&Tw[l16*128 + kk*32 + quad*8];
  __syncthreads();                                 // Tw reads done before W2 buf1 overwrite

  // stage W2 chunk0 (W1 chunk0 already resident from prologue)
  stageW2(0, 0);
  asm volatile("s_waitcnt vmcnt(0)" ::: "memory");
  __syncthreads();

  #pragma unroll
  for (int nt = 0; nt < 8; ++nt){ O[nt][0]=0.f; O[nt][1]=0.f; O[nt][2]=0.f; O[nt][3]=0.f; }

  for (int c = 0; c < 32; ++c){
    const int buf = c & 1;
    if (c + 1 < 32){ stageW1(buf ^ 1, (c + 1)*64); stageW2(buf ^ 1, (c + 1)*64); }

    #pragma unroll
    for (int nt = 0; nt < 4; ++nt){
      int row = nt*16 + l16;
      bf16x8 wf[4];
      #pragma unroll
      for (int kk = 0; kk < 4; ++kk)
        wf[kk] = *(const bf16x8*)&SM[buf*8192 + (row*16 + ((kk*4 + quad) ^ l16))*8];
      float b1v = b1[c*64 + row];
      f32x4 s = {0.f,0.f,0.f,0.f};
      #pragma unroll
      for (int kk = 0; kk < 4; ++kk)
        s = __builtin_amdgcn_mfma_f32_16x16x32_bf16(af[kk], wf[kk], s, 0, 0, 0);
      #pragma unroll
      for (int rr = 0; rr < 4; ++rr)
        Pw[(quad*4 + rr)*72 + nt*16 + l16] = f2bf(fmaxf(s[rr] + b1v, 0.f));
    }
    asm volatile("s_waitcnt lgkmcnt(0)" ::: "memory");

    bf16x8 pf[2];
    #pragma unroll
    for (int kk = 0; kk < 2; ++kk)
      pf[kk] = *(const bf16x8*)&Pw[l16*72 + kk*32 + quad*8];
    #pragma unroll
    for (int nt = 0; nt < 8; ++nt){
      int row = nt*16 + l16;
      bf16x8 wf[2];
      #pragma unroll
      for (int kk = 0; kk < 2; ++kk)
        wf[kk] = *(const bf16x8*)&SM[16384 + buf*8192 + (row*8 + ((kk*4 + quad) ^ (l16 & 7)))*8];
      #pragma unroll
      for (int kk = 0; kk < 2; ++kk)
        O[nt] = __builtin_amdgcn_mfma_f32_16x16x32_bf16(pf[kk], wf[kk], O[nt], 0, 0, 0);
    }

    if (c + 1 < 32){
      asm volatile("s_waitcnt vmcnt(0)" ::: "memory");
      __syncthreads();
    }
  }

  #pragma unroll
  for (int rr = 0; rr < 4; ++rr){
    int row = m0 + wave*16 + quad*4 + rr;
    float vs[8], sum = 0.f;
    #pragma unroll
    for (int nt = 0; nt < 8; ++nt){
      int col = nt*16 + l16;
      float v = O[nt][rr] + b2[col] + res[nt][rr];
      vs[nt] = v; sum += v;
    }
    sum += __shfl_xor(sum, 1); sum += __shfl_xor(sum, 2);
    sum += __shfl_xor(sum, 4); sum += __shfl_xor(sum, 8);
    float mean = sum * (1.f/DD);
    float sq = 0.f;
    #pragma unroll
    for (int nt = 0; nt < 8; ++nt){ float d = vs[nt] - mean; sq += d*d; }
    sq += __shfl_xor(sq, 1); sq += __shfl_xor(sq, 2);
    sq += __shfl_xor(sq, 4); sq += __shfl_xor(sq, 8);
    float rs = rsqrtf(sq * (1.f/DD) + 1e-5f);
    #pragma unroll
    for (int nt = 0; nt < 8; ++nt){
      int col = nt*16 + l16;
      float o = (vs[nt] - mean)*rs*g2[col] + beta2[col];
      cur[(size_t)row*DD + col]  = o;
      curb[(size_t)row*DD + col] = f2bf(o);
    }
  }
}

// ---------------- final masked mean, two-stage ----------------
__global__ __launch_bounds__(128) void reduce1_kernel(
    const float* __restrict__ cur, const float* __restrict__ mask,
    float* __restrict__ partial, float* __restrict__ cnt)
{
  int b = blockIdx.x, c = blockIdx.y, t = threadIdx.x;
  float acc = 0.f, cn = 0.f;
  for (int s = c*128; s < c*128 + 128; ++s){
    float mk = mask[b*NPER + s];
    acc += cur[(size_t)(b*NPER + s)*DD + t] * mk;
    cn += mk;
  }
  partial[(size_t)(b*8 + c)*DD + t] = acc;
  if (t == 0) cnt[b*8 + c] = cn;
}
__global__ __launch_bounds__(128) void reduce2_kernel(
    const float* __restrict__ partial, const float* __restrict__ cnt,
    const int* __restrict__ flag, void* __restrict__ out)
{
  int b = blockIdx.x, t = threadIdx.x;
  float acc = 0.f, cn = 0.f;
  #pragma unroll
  for (int c = 0; c < 8; ++c){
    acc += partial[(size_t)(b*8 + c)*DD + t];
    cn  += cnt[b*8 + c];
  }
  float val = acc / cn;
  if (*flag) ((u16*)out)[b*DD + t] = f2bf(val);
  else       ((float*)out)[b*DD + t] = val;
}

// ---------------- host ----------------
extern "C" void kernel_launch(void* const* d_in, const int* in_sizes, int n_in,
                              void* d_out, int out_size, void* d_ws, size_t ws_size,
                              hipStream_t stream)
{
  (void)in_sizes; (void)n_in; (void)out_size; (void)ws_size;
  char* ws = (char*)d_ws;
  int*   flag   = (int*)(ws + OFF_FLAG);
  int*   starts = (int*)(ws + OFF_STARTS);
  float* BIN  = (float*)(ws + OFF_BIN);
  float* BQKV = (float*)(ws + OFF_BQKV);
  float* BO   = (float*)(ws + OFF_BO);
  float* B1   = (float*)(ws + OFF_B1);
  float* B2   = (float*)(ws + OFF_B2);
  float* LN1G = (float*)(ws + OFF_LN1G);
  float* LN1B = (float*)(ws + OFF_LN1B);
  float* LN2G = (float*)(ws + OFF_LN2G);
  float* LN2B = (float*)(ws + OFF_LN2B);
  u16* WINB  = (u16*)(ws + OFF_WINB);
  u16* WQKVB = (u16*)(ws + OFF_WQKVB);
  u16* WOB   = (u16*)(ws + OFF_WOB);
  u16* W1B   = (u16*)(ws + OFF_W1B);
  u16* W2B   = (u16*)(ws + OFF_W2B);
  float* CUR = (float*)(ws + OFF_CUR);
  u16* CURB  = (u16*)(ws + OFF_CURB);
  u16* QH    = (u16*)(ws + OFF_QKVB);
  u16* KT    = (u16*)(ws + OFF_QKVB + (size_t)4194304*2);
  u16* ATTNOB= (u16*)(ws + OFF_ATTNOB);
  float* MASK= (float*)(ws + OFF_MASK);
  u16* VTB   = (u16*)(ws + OFF_VT);
  float* RED = (float*)(ws + OFF_RED);
  float* CNT = (float*)(ws + OFF_CNT);

  prep_kernel<<<1, 256, 0, stream>>>((const unsigned*)d_in[0], (const int*)d_in[1],
                                     flag, starts);

  ConvArgs ca;
  ca.s[0]  = { d_in[2],  WINB,  DD*INDIM,   1 };
  ca.s[1]  = { d_in[4],  WQKVB, LL*3*DD*DD, 1 };
  ca.s[2]  = { d_in[6],  WOB,   LL*DD*DD,   1 };
  ca.s[3]  = { d_in[8],  W1B,   LL*DFF*DD,  1 };
  ca.s[4]  = { d_in[10], W2B,   LL*DD*DFF,  1 };
  ca.s[5]  = { d_in[3],  BIN,   DD,         0 };
  ca.s[6]  = { d_in[5],  BQKV,  LL*3*DD,    0 };
  ca.s[7]  = { d_in[7],  BO,    LL*DD,      0 };
  ca.s[8]  = { d_in[9],  B1,    LL*DFF,     0 };
  ca.s[9]  = { d_in[11], B2,    LL*DD,      0 };
  ca.s[10] = { d_in[12], LN1G,  LL*DD,      0 };
  ca.s[11] = { d_in[13], LN1B,  LL*DD,      0 };
  ca.s[12] = { d_in[14], LN2G,  LL*DD,      0 };
  ca.s[13] = { d_in[15], LN2B,  LL*DD,      0 };
  int nblk = 0;
  for (int i = 0; i < 14; ++i) nblk += (ca.s[i].n + 1023) >> 10;
  convall_kernel<<<nblk, 256, 0, stream>>>(ca, flag);

  inproj_kernel<<<NTOT/64, 256, 0, stream>>>(
      d_in[0], WINB, BIN, (const int*)d_in[1], starts, flag, CUR, CURB, MASK);

  for (int l = 0; l < LL; ++l){
    wgemm2_kernel<<<dim3(NTOT/128, 3), 256, 0, stream>>>(
        CURB, WQKVB + (size_t)l*3*DD*DD, BQKV + l*3*DD, QH, KT, VTB);
    fattn_kernel<<<dim3(NPER/128, HH, BB), 256, 0, stream>>>(QH, KT, VTB, ATTNOB);
    ffn_kernel<<<dim3(NTOT/64), 256, 0, stream>>>(
        ATTNOB, WOB + (size_t)l*DD*DD, BO + l*DD, LN1G + l*DD, LN1B + l*DD,
        W1B + (size_t)l*DFF*DD, W2B + (size_t)l*DD*DFF,
        B1 + l*DFF, B2 + l*DD, LN2G + l*DD, LN2B + l*DD, CUR, CURB);
  }

  reduce1_kernel<<<dim3(BB, 8), 128, 0, stream>>>(CUR, MASK, RED, CNT);
  reduce2_kernel<<<BB, 128, 0, stream>>>(RED, CNT, flag, d_out);
}

// Round 21
// 452.827 us; speedup vs baseline: 1.0799x; 1.0799x over previous
//
#include <hip/hip_runtime.h>
#include <hip/hip_bf16.h>
#include <stdint.h>

// ---------------- static problem sizes ----------------
#define BB    32
#define NPER  1024
#define NTOT  32768
#define DD    128
#define HH    4
#define HD    32
#define LL    3
#define DFF   2048
#define INDIM 64

// Softmax exp: prefer raw v_exp_f32 (base-2) with log2(e) folded into the Q
// scale. Guarded: plain exp2f() lowers to the precise OCML path (R20: +9 us/
// dispatch); __expf is the measured-good fallback (R19: 461.3 us total).
#if __has_builtin(__builtin_amdgcn_exp2f)
#define PEXP(x) __builtin_amdgcn_exp2f(x)
#define QKSCALE 0.2550348635f            /* (1/sqrt(32)) * log2(e) */
#else
#define PEXP(x) __expf(x)
#define QKSCALE 0.17677669529663687f     /* 1/sqrt(32) */
#endif

typedef unsigned short u16;
typedef short bf16x8 __attribute__((ext_vector_type(8)));   // 8 bf16 (4 VGPRs)
typedef float f32x4 __attribute__((ext_vector_type(4)));

// address-space casts for global_load_lds (direct global->LDS DMA)
#define AS_GLOBAL(p) ((const __attribute__((address_space(1))) void*)(p))
#define AS_LDS(p)    ((__attribute__((address_space(3))) void*)(p))

__device__ __forceinline__ float bf2f(u16 v){
  unsigned u = ((unsigned)v) << 16; float f; __builtin_memcpy(&f, &u, 4); return f;
}
__device__ __forceinline__ u16 f2bf(float f){
  unsigned u; __builtin_memcpy(&u, &f, 4);
  unsigned lsb = (u >> 16) & 1u;
  u += 0x7fffu + lsb;              // round-to-nearest-even
  return (u16)(u >> 16);
}
// pack two f32 -> two bf16 by truncation (3 ops; P-values only: <=0.2% bias)
__device__ __forceinline__ unsigned pk_bf_trunc(float a, float b){
  unsigned ua, ub;
  __builtin_memcpy(&ua, &a, 4); __builtin_memcpy(&ub, &b, 4);
  return (ub & 0xFFFF0000u) | (ua >> 16);
}

// ---------------- workspace layout (bytes) ----------------
constexpr size_t OFF_FLAG   = 0;
constexpr size_t OFF_STARTS = 256;
constexpr size_t OFF_BIN    = 1024;
constexpr size_t OFF_BQKV   = OFF_BIN   + 128*4;
constexpr size_t OFF_BO     = OFF_BQKV  + 1152*4;
constexpr size_t OFF_B1     = OFF_BO    + 384*4;
constexpr size_t OFF_B2     = OFF_B1    + 6144*4;
constexpr size_t OFF_LN1G   = OFF_B2    + 384*4;
constexpr size_t OFF_LN1B   = OFF_LN1G  + 384*4;
constexpr size_t OFF_LN2G   = OFF_LN1B  + 384*4;
constexpr size_t OFF_LN2B   = OFF_LN2G  + 384*4;
constexpr size_t OFF_XB     = 40960;                               // (unused)
constexpr size_t OFF_WINB   = OFF_XB    + (size_t)2097152*2;
constexpr size_t OFF_WQKVB  = OFF_WINB  + (size_t)8192*2;
constexpr size_t OFF_WOB    = OFF_WQKVB + (size_t)147456*2;
constexpr size_t OFF_W1B    = OFF_WOB   + (size_t)49152*2;
constexpr size_t OFF_W2B    = OFF_W1B   + (size_t)786432*2;
constexpr size_t OFF_CUR    = OFF_W2B   + (size_t)786432*2;
constexpr size_t OFF_TMP    = OFF_CUR   + (size_t)4194304*4;      // (unused)
constexpr size_t OFF_CURB   = OFF_TMP   + (size_t)4194304*4;
constexpr size_t OFF_QKVB   = OFF_CURB  + (size_t)4194304*2;      // QH (8 MB) + KT (8 MB)
constexpr size_t OFF_ATTNOB = OFF_QKVB  + (size_t)12582912*2;
constexpr size_t OFF_ACTB   = OFF_ATTNOB+ (size_t)4194304*2;      // (unused)
constexpr size_t OFF_MASK   = OFF_ACTB  + (size_t)16777216*2;
constexpr size_t OFF_VT     = OFF_MASK  + (size_t)NTOT*4;         // VTile (8 MB)
constexpr size_t OFF_RED    = OFF_VT    + (size_t)4096*1024*2;
constexpr size_t OFF_CNT    = OFF_RED   + (size_t)32*8*128*4;

// ---------------- dtype detection + graph starts (one launch) ----------------
__device__ __forceinline__ int plaus(unsigned bits){
  if ((bits << 1) == 0u) return 1;
  unsigned e = (bits >> 23) & 0xFFu;
  return (e >= 100u && e <= 140u) ? 1 : 0;
}
__global__ void prep_kernel(const unsigned* __restrict__ x, const int* __restrict__ batch,
                            int* __restrict__ flag, int* __restrict__ starts){
  __shared__ int red[256];
  int t = threadIdx.x, c = 0;
  for (int i = t; i < 2048; i += 256){
    unsigned w = x[i];
    c += (plaus(w << 16) & plaus(w & 0xFFFF0000u));
  }
  red[t] = c; __syncthreads();
  for (int s = 128; s > 0; s >>= 1){ if (t < s) red[t] += red[t+s]; __syncthreads(); }
  if (t == 0) *flag = (red[0] >= 1229) ? 1 : 0;
  if (t < BB){
    int lo = 0, hi = NTOT;
    while (lo < hi){ int mid = (lo + hi) >> 1; if (batch[mid] < t) lo = mid + 1; else hi = mid; }
    starts[t] = lo;
  }
}

// ---------------- fused conversion of weight/bias tensors (1 launch) ----------------
struct ConvSeg { const void* src; void* dst; int n; int tobf; };
struct ConvArgs { ConvSeg s[14]; };

__global__ __launch_bounds__(256) void convall_kernel(ConvArgs a, const int* __restrict__ flag){
  const int isb = *flag;
  const int blk = blockIdx.x;
  int seg = -1, base = 0, lb = 0;
  #pragma unroll
  for (int i = 0; i < 14; ++i){
    int nb = (a.s[i].n + 1023) >> 10;
    if (seg < 0){
      if (blk < base + nb){ seg = i; lb = blk - base; }
      base += nb;
    }
  }
  const ConvSeg sg = a.s[seg];
  const int idx = lb*1024 + threadIdx.x*4;
  if (idx >= sg.n) return;
  if (sg.tobf){
    u16* dst = (u16*)sg.dst + idx;
    if (isb){
      *(uint2*)dst = *(const uint2*)((const u16*)sg.src + idx);
    } else {
      const float* s4 = (const float*)sg.src + idx;
      dst[0] = f2bf(s4[0]); dst[1] = f2bf(s4[1]);
      dst[2] = f2bf(s4[2]); dst[3] = f2bf(s4[3]);
    }
  } else {
    float* dst = (float*)sg.dst + idx;
    if (isb){
      const u16* s4 = (const u16*)sg.src + idx;
      dst[0] = bf2f(s4[0]); dst[1] = bf2f(s4[1]);
      dst[2] = bf2f(s4[2]); dst[3] = bf2f(s4[3]);
    } else {
      *(float4*)dst = *(const float4*)((const float*)sg.src + idx);
    }
  }
}

// ---------------- fused input projection + scatter + mask (dual-dtype x) ----------------
__global__ __launch_bounds__(256) void inproj_kernel(
    const void* __restrict__ xraw,    // [NTOT][64] bf16 or f32 (per flag)
    const u16* __restrict__ WINB,     // [128][64] bf16
    const float* __restrict__ bin,    // [128]
    const int* __restrict__ batch, const int* __restrict__ starts,
    const int* __restrict__ flag,
    float* __restrict__ cur, u16* __restrict__ curb, float* __restrict__ mask)
{
  __shared__ __align__(16) u16 Wl[8192];           // 128 rows x 64 k, XOR8 swizzle
  const int t = threadIdx.x, wave = t >> 6, lane = t & 63;
  const int quad = lane >> 4, l16 = lane & 15;
  const int m0 = blockIdx.x * 64;
  const int isb = *flag;

  #pragma unroll
  for (int j = 0; j < 4; ++j){
    int s = t + 256*j;
    int r = s >> 3, c8 = (s & 7) ^ (r & 7);
    *(uint4*)&Wl[s*8] = *(const uint4*)(WINB + (size_t)r*INDIM + c8*8);
  }
  bf16x8 af[2];
  const int arow = m0 + wave*16 + l16;
  if (isb){
    const u16* XB = (const u16*)xraw;
    #pragma unroll
    for (int kk = 0; kk < 2; ++kk)
      af[kk] = *(const bf16x8*)(XB + (size_t)arow*INDIM + kk*32 + quad*8);
  } else {
    const float* Xf = (const float*)xraw;
    #pragma unroll
    for (int kk = 0; kk < 2; ++kk){
      float4 a = *(const float4*)(Xf + (size_t)arow*INDIM + kk*32 + quad*8);
      float4 b = *(const float4*)(Xf + (size_t)arow*INDIM + kk*32 + quad*8 + 4);
      af[kk][0] = (short)f2bf(a.x); af[kk][1] = (short)f2bf(a.y);
      af[kk][2] = (short)f2bf(a.z); af[kk][3] = (short)f2bf(a.w);
      af[kk][4] = (short)f2bf(b.x); af[kk][5] = (short)f2bf(b.y);
      af[kk][6] = (short)f2bf(b.z); af[kk][7] = (short)f2bf(b.w);
    }
  }
  __syncthreads();

  f32x4 O[8];
  #pragma unroll
  for (int nt = 0; nt < 8; ++nt){ O[nt][0]=0.f; O[nt][1]=0.f; O[nt][2]=0.f; O[nt][3]=0.f; }

  #pragma unroll
  for (int nt = 0; nt < 8; ++nt){
    int row = nt*16 + l16;
    bf16x8 wf[2];
    #pragma unroll
    for (int kk = 0; kk < 2; ++kk)
      wf[kk] = *(const bf16x8*)&Wl[(row*8 + ((kk*4 + quad) ^ (row & 7)))*8];
    #pragma unroll
    for (int kk = 0; kk < 2; ++kk)
      O[nt] = __builtin_amdgcn_mfma_f32_16x16x32_bf16(af[kk], wf[kk], O[nt], 0, 0, 0);
  }

  #pragma unroll
  for (int rr = 0; rr < 4; ++rr){
    int node = m0 + wave*16 + quad*4 + rr;
    int gr = batch[node];
    int p  = node - starts[gr];
    float vs[8], sum = 0.f;
    #pragma unroll
    for (int nt = 0; nt < 8; ++nt){
      float v = O[nt][rr] + bin[nt*16 + l16];
      vs[nt] = v; sum += v;
    }
    sum += __shfl_xor(sum, 1); sum += __shfl_xor(sum, 2);
    sum += __shfl_xor(sum, 4); sum += __shfl_xor(sum, 8);
    if ((unsigned)p < (unsigned)NPER && (unsigned)gr < (unsigned)BB){
      size_t j = (size_t)gr*NPER + p;
      #pragma unroll
      for (int nt = 0; nt < 8; ++nt){
        int col = nt*16 + l16;
        cur[j*DD + col]  = vs[nt];
        curb[j*DD + col] = f2bf(vs[nt]);
      }
      if (l16 == 0) mask[j] = (sum != 0.f) ? 1.f : 0.f;
    }
  }
}

// ---------------- MFMA flash attention (R19-best structure, guarded exp) ----------------
__global__ __launch_bounds__(256) void fattn_kernel(
    const u16* __restrict__ qh,     // [BH][NPER][32]
    const u16* __restrict__ ktb,    // [BH][NPER*32] tiled
    const u16* __restrict__ vtb,    // [BH][NPER*32] tiled
    u16* __restrict__ attnob)       // [NTOT][128]
{
  __shared__ __align__(16) u16 Klds[2][2048];      // [c(4)][r(64)][8]
  __shared__ __align__(16) u16 Vl[2][2048];        // [cv(8)][d(32)][8]
  __shared__ __align__(16) u16 Pl[4][2][16*72];    // per-(wave,qt) P [q][s], pitch 72

  const int t = threadIdx.x;
  const int wave = t >> 6, lane = t & 63;
  const int quad = lane >> 4, l16 = lane & 15;
  const int q0 = blockIdx.x * 128;
  const int h = blockIdx.y, b = blockIdx.z;
  const size_t bh = (size_t)(b*HH + h) * NPER * 32;
  const u16* Qg = qh + bh;
  const u16* Kg = ktb + bh;
  const u16* Vg = vtb + bh;

  bf16x8 qf[2];
  #pragma unroll
  for (int qt = 0; qt < 2; ++qt){
    uint4 qv = *(const uint4*)(Qg + (size_t)(q0 + wave*32 + qt*16 + l16)*32 + quad*8);
    u16 raw[8]; __builtin_memcpy(raw, &qv, 16);
    #pragma unroll
    for (int j = 0; j < 8; ++j) qf[qt][j] = (short)f2bf(bf2f(raw[j]) * QKSCALE);
  }

  auto stage = [&](int buf, int kt){
    __builtin_amdgcn_global_load_lds(
        AS_GLOBAL(Kg + kt*2048 + wave*512 + lane*8),
        AS_LDS(&Klds[buf][wave*64*8]), 16, 0, 0);
    __builtin_amdgcn_global_load_lds(
        AS_GLOBAL(Vg + kt*2048 + wave*512 + lane*8),
        AS_LDS(&Vl[buf][wave*64*8]), 16, 0, 0);
  };

  float lsum[2] = {0.f, 0.f};
  f32x4 o[2][2];
  #pragma unroll
  for (int qt = 0; qt < 2; ++qt)
    #pragma unroll
    for (int i = 0; i < 2; ++i){ o[qt][i][0]=0.f; o[qt][i][1]=0.f; o[qt][i][2]=0.f; o[qt][i][3]=0.f; }

  stage(0, 0);
  asm volatile("s_waitcnt vmcnt(0)" ::: "memory");
  __syncthreads();

  for (int kt = 0; kt < 16; ++kt){
    const int buf = kt & 1;
    if (kt + 1 < 16) stage(buf ^ 1, kt + 1);

    f32x4 sfr[2][4];
    #pragma unroll
    for (int nt = 0; nt < 4; ++nt){
      bf16x8 kf = *(const bf16x8*)&Klds[buf][(quad*64 + nt*16 + l16)*8];
      f32x4 z = {0.f,0.f,0.f,0.f};
      sfr[0][nt] = __builtin_amdgcn_mfma_f32_16x16x32_bf16(kf, qf[0], z, 0, 0, 0);
      sfr[1][nt] = __builtin_amdgcn_mfma_f32_16x16x32_bf16(kf, qf[1], z, 0, 0, 0);
    }

    #pragma unroll
    for (int qt = 0; qt < 2; ++qt){
      float ps = 0.f;
      #pragma unroll
      for (int nt = 0; nt < 4; ++nt){
        float e0 = PEXP(sfr[qt][nt][0]), e1 = PEXP(sfr[qt][nt][1]);
        float e2 = PEXP(sfr[qt][nt][2]), e3 = PEXP(sfr[qt][nt][3]);
        ps += (e0 + e1) + (e2 + e3);
        uint2 w;
        w.x = pk_bf_trunc(e0, e1);
        w.y = pk_bf_trunc(e2, e3);
        *(uint2*)&Pl[wave][qt][l16*72 + nt*16 + quad*4] = w;
      }
      ps += __shfl_xor(ps, 16);
      ps += __shfl_xor(ps, 32);
      lsum[qt] += ps;
    }
    asm volatile("s_waitcnt lgkmcnt(0)" ::: "memory");

    #pragma unroll
    for (int kk = 0; kk < 2; ++kk){
      bf16x8 v0 = *(const bf16x8*)&Vl[buf][((kk*4 + quad)*32 + l16)*8];
      bf16x8 v1 = *(const bf16x8*)&Vl[buf][((kk*4 + quad)*32 + 16 + l16)*8];
      #pragma unroll
      for (int qt = 0; qt < 2; ++qt){
        bf16x8 pf = *(const bf16x8*)&Pl[wave][qt][l16*72 + kk*32 + quad*8];
        o[qt][0] = __builtin_amdgcn_mfma_f32_16x16x32_bf16(pf, v0, o[qt][0], 0, 0, 0);
        o[qt][1] = __builtin_amdgcn_mfma_f32_16x16x32_bf16(pf, v1, o[qt][1], 0, 0, 0);
      }
    }

    if (kt + 1 < 16){
      asm volatile("s_waitcnt vmcnt(0)" ::: "memory");
      __syncthreads();
    }
  }

  #pragma unroll
  for (int qt = 0; qt < 2; ++qt){
    #pragma unroll
    for (int r = 0; r < 4; ++r){
      float inv = 1.f / __shfl(lsum[qt], quad*4 + r);
      int row = q0 + wave*32 + qt*16 + quad*4 + r;
      size_t base = (size_t)(b*NPER + row)*DD + h*HD;
      attnob[base + l16]      = f2bf(o[qt][0][r] * inv);
      attnob[base + 16 + l16] = f2bf(o[qt][1][r] * inv);
    }
  }
}

// ---------------- QKV GEMM: 128-row blocks, wave owns 32 rows, head-major out ----------------
__global__ __launch_bounds__(256) void wgemm2_kernel(
    const u16* __restrict__ A,        // [M][128] bf16
    const u16* __restrict__ Wbase,    // [3*128][128] bf16
    const float* __restrict__ biasb,  // [3*128]
    u16* __restrict__ qh, u16* __restrict__ ktb, u16* __restrict__ vtb)
{
  __shared__ __align__(16) u16 Wl[16384];          // 128x128, XOR-swizzled chunks
  const int t = threadIdx.x, wave = t >> 6, lane = t & 63;
  const int quad = lane >> 4, l16 = lane & 15;
  const int m0 = blockIdx.x * 128, nb = blockIdx.y;
  const u16* Wsl = Wbase + (size_t)nb * 16384;
  const float* bias = biasb + nb * 128;

  #pragma unroll
  for (int j = 0; j < 8; ++j){
    int s = t + 256*j;
    int r = s >> 4, cx = (s & 15) ^ (r & 15);
    *(uint4*)&Wl[s*8] = *(const uint4*)(Wsl + (size_t)r*128 + cx*8);
  }
  bf16x8 af[2][4];
  #pragma unroll
  for (int mt = 0; mt < 2; ++mt)
    #pragma unroll
    for (int kk = 0; kk < 4; ++kk)
      af[mt][kk] = *(const bf16x8*)(A + (size_t)(m0 + wave*32 + mt*16 + l16)*128 + kk*32 + quad*8);
  __syncthreads();

  f32x4 O[2][8];
  #pragma unroll
  for (int mt = 0; mt < 2; ++mt)
    #pragma unroll
    for (int nt = 0; nt < 8; ++nt){ O[mt][nt][0]=0.f; O[mt][nt][1]=0.f; O[mt][nt][2]=0.f; O[mt][nt][3]=0.f; }

  #pragma unroll
  for (int nt = 0; nt < 8; ++nt){
    int row = nt*16 + l16;
    bf16x8 wf[4];
    #pragma unroll
    for (int kk = 0; kk < 4; ++kk)
      wf[kk] = *(const bf16x8*)&Wl[(row*16 + ((kk*4 + quad) ^ l16))*8];
    #pragma unroll
    for (int mt = 0; mt < 2; ++mt)
      #pragma unroll
      for (int kk = 0; kk < 4; ++kk)
        O[mt][nt] = __builtin_amdgcn_mfma_f32_16x16x32_bf16(af[mt][kk], wf[kk], O[mt][nt], 0, 0, 0);
  }

  if (nb == 0){
    #pragma unroll
    for (int mt = 0; mt < 2; ++mt)
      #pragma unroll
      for (int rr = 0; rr < 4; ++rr){
        int s = m0 + wave*32 + mt*16 + quad*4 + rr;
        int bg = s >> 10, sl = s & 1023;
        #pragma unroll
        for (int nt = 0; nt < 8; ++nt){
          int col = nt*16 + l16, hh = col >> 5, d = col & 31;
          qh[((size_t)(bg*HH + hh)*NPER + sl)*32 + d] = f2bf(O[mt][nt][rr] + bias[col]);
        }
      }
  } else if (nb == 1){
    #pragma unroll
    for (int mt = 0; mt < 2; ++mt)
      #pragma unroll
      for (int rr = 0; rr < 4; ++rr){
        int s = m0 + wave*32 + mt*16 + quad*4 + rr;
        int bg = s >> 10, sl = s & 1023;
        int kt = sl >> 6, r = sl & 63;
        #pragma unroll
        for (int nt = 0; nt < 8; ++nt){
          int col = nt*16 + l16, hh = col >> 5, d = col & 31;
          ktb[(size_t)(bg*HH + hh)*NPER*32 + kt*2048 + (d>>3)*512 + r*8 + (d&7)]
              = f2bf(O[mt][nt][rr] + bias[col]);
        }
      }
  } else {
    #pragma unroll
    for (int mt = 0; mt < 2; ++mt){
      int rowb = m0 + wave*32 + mt*16 + quad*4;
      int bg = rowb >> 10, sl = rowb & 1023;
      int kt = sl >> 6, cv = (sl & 63) >> 3, j0 = sl & 7;
      #pragma unroll
      for (int nt = 0; nt < 8; ++nt){
        int col = nt*16 + l16, hh = col >> 5, d = col & 31;
        float v0 = O[mt][nt][0] + bias[col], v1 = O[mt][nt][1] + bias[col];
        float v2 = O[mt][nt][2] + bias[col], v3 = O[mt][nt][3] + bias[col];
        uint2 w;
        w.x = (unsigned)f2bf(v0) | ((unsigned)f2bf(v1) << 16);
        w.y = (unsigned)f2bf(v2) | ((unsigned)f2bf(v3) << 16);
        *(uint2*)(vtb + (size_t)(bg*HH + hh)*NPER*32 + kt*2048 + cv*256 + d*8 + j0) = w;
      }
    }
  }
}

// ---------------- fused Wo+LN1+FFN+LN2 (R17-measured best: BK=64, 2 blocks/CU) ----------------
__global__ __launch_bounds__(256, 2) void ffn_kernel(
    const u16* __restrict__ attnob,   // [M][128] bf16
    const u16* __restrict__ Wog,      // [128][128] bf16
    const float* __restrict__ bo,
    const float* __restrict__ g1, const float* __restrict__ beta1,
    const u16* __restrict__ W1g,      // [2048][128]
    const u16* __restrict__ W2g,      // [128][2048]
    const float* __restrict__ b1,
    const float* __restrict__ b2,
    const float* __restrict__ g2, const float* __restrict__ beta2,
    float* __restrict__ cur, u16* __restrict__ curb)
{
  // carved LDS: [0,16384) W1l dbuf, [16384,32768) W2l dbuf, [32768,37376) Pl
  __shared__ __align__(16) u16 SM[37376];
  const int t = threadIdx.x, wave = t >> 6, lane = t & 63;
  const int quad = lane >> 4, l16 = lane & 15;
  const int m0 = blockIdx.x * 64;
  u16* Pw = &SM[32768 + wave*1152];

  auto stageW1 = [&](int buf, int dffc){
    #pragma unroll
    for (int i = 0; i < 4; ++i){
      const int s0 = wave*256 + i*64;
      const int s  = s0 + lane;
      int r = s >> 4, cx = (s & 15) ^ (r & 15);
      __builtin_amdgcn_global_load_lds(
          AS_GLOBAL(W1g + (size_t)(dffc + r)*128 + cx*8),
          AS_LDS(&SM[buf*8192 + s0*8]), 16, 0, 0);
    }
  };
  auto stageW2 = [&](int buf, int dffc){
    #pragma unroll
    for (int i = 0; i < 4; ++i){
      const int s0 = wave*256 + i*64;
      const int s  = s0 + lane;
      int r = s >> 3, cx = (s & 7) ^ (r & 7);
      __builtin_amdgcn_global_load_lds(
          AS_GLOBAL(W2g + (size_t)r*DFF + dffc + cx*8),
          AS_LDS(&SM[16384 + buf*8192 + s0*8]), 16, 0, 0);
    }
  };

  // ---- prologue: Wo into W2l region + W1 chunk0 into W1l buf0 (overlapped) ----
  #pragma unroll
  for (int i = 0; i < 8; ++i){
    int s0 = wave*512 + i*64;
    int s = s0 + lane;
    int r = s >> 4, cx = (s & 15) ^ (r & 15);
    __builtin_amdgcn_global_load_lds(
        AS_GLOBAL(Wog + (size_t)r*128 + cx*8),
        AS_LDS(&SM[16384 + s0*8]), 16, 0, 0);
  }
  stageW1(0, 0);                                   // W1l region idle during prologue
  bf16x8 afo[4];
  #pragma unroll
  for (int kk = 0; kk < 4; ++kk)
    afo[kk] = *(const bf16x8*)(attnob + (size_t)(m0 + wave*16 + l16)*128 + kk*32 + quad*8);
  asm volatile("s_waitcnt vmcnt(0)" ::: "memory");
  __syncthreads();

  f32x4 O[8];
  #pragma unroll
  for (int nt = 0; nt < 8; ++nt){ O[nt][0]=0.f; O[nt][1]=0.f; O[nt][2]=0.f; O[nt][3]=0.f; }
  #pragma unroll
  for (int nt = 0; nt < 8; ++nt){
    int row = nt*16 + l16;
    bf16x8 wf[4];
    #pragma unroll
    for (int kk = 0; kk < 4; ++kk)
      wf[kk] = *(const bf16x8*)&SM[16384 + (row*16 + ((kk*4 + quad) ^ l16))*8];
    #pragma unroll
    for (int kk = 0; kk < 4; ++kk)
      O[nt] = __builtin_amdgcn_mfma_f32_16x16x32_bf16(afo[kk], wf[kk], O[nt], 0, 0, 0);
  }

  float res[8][4];
  u16* Tw = &SM[24576 + wave*2048];                // 16 rows x pitch 128, W2l buf1 region
  #pragma unroll
  for (int rr = 0; rr < 4; ++rr){
    int row = m0 + wave*16 + quad*4 + rr;
    float vs[8], sum = 0.f;
    #pragma unroll
    for (int nt = 0; nt < 8; ++nt){
      int col = nt*16 + l16;
      float v = O[nt][rr] + bo[col] + cur[(size_t)row*DD + col];
      vs[nt] = v; sum += v;
    }
    sum += __shfl_xor(sum, 1); sum += __shfl_xor(sum, 2);
    sum += __shfl_xor(sum, 4); sum += __shfl_xor(sum, 8);
    float mean = sum * (1.f/DD);
    float sq = 0.f;
    #pragma unroll
    for (int nt = 0; nt < 8; ++nt){ float d = vs[nt] - mean; sq += d*d; }
    sq += __shfl_xor(sq, 1); sq += __shfl_xor(sq, 2);
    sq += __shfl_xor(sq, 4); sq += __shfl_xor(sq, 8);
    float rs = rsqrtf(sq * (1.f/DD) + 1e-5f);
    #pragma unroll
    for (int nt = 0; nt < 8; ++nt){
      int col = nt*16 + l16;
      float o = (vs[nt] - mean)*rs*g1[col] + beta1[col];
      res[nt][rr] = o;
      Tw[(quad*4 + rr)*128 + col] = f2bf(o);
    }
  }
  asm volatile("s_waitcnt lgkmcnt(0)" ::: "memory");

  bf16x8 af[4];
  #pragma unroll
  for (int kk = 0; kk < 4; ++kk)
    af[kk] = *(const bf16x8*)&Tw[l16*128 + kk*32 + quad*8];
  __syncthreads();                                 // Tw reads done before W2 buf1 overwrite

  // stage W2 chunk0 (W1 chunk0 already resident from prologue)
  stageW2(0, 0);
  asm volatile("s_waitcnt vmcnt(0)" ::: "memory");
  __syncthreads();

  #pragma unroll
  for (int nt = 0; nt < 8; ++nt){ O[nt][0]=0.f; O[nt][1]=0.f; O[nt][2]=0.f; O[nt][3]=0.f; }

  for (int c = 0; c < 32; ++c){
    const int buf = c & 1;
    if (c + 1 < 32){ stageW1(buf ^ 1, (c + 1)*64); stageW2(buf ^ 1, (c + 1)*64); }

    #pragma unroll
    for (int nt = 0; nt < 4; ++nt){
      int row = nt*16 + l16;
      bf16x8 wf[4];
      #pragma unroll
      for (int kk = 0; kk < 4; ++kk)
        wf[kk] = *(const bf16x8*)&SM[buf*8192 + (row*16 + ((kk*4 + quad) ^ l16))*8];
      float b1v = b1[c*64 + row];
      f32x4 s = {0.f,0.f,0.f,0.f};
      #pragma unroll
      for (int kk = 0; kk < 4; ++kk)
        s = __builtin_amdgcn_mfma_f32_16x16x32_bf16(af[kk], wf[kk], s, 0, 0, 0);
      #pragma unroll
      for (int rr = 0; rr < 4; ++rr)
        Pw[(quad*4 + rr)*72 + nt*16 + l16] = f2bf(fmaxf(s[rr] + b1v, 0.f));
    }
    asm volatile("s_waitcnt lgkmcnt(0)" ::: "memory");

    bf16x8 pf[2];
    #pragma unroll
    for (int kk = 0; kk < 2; ++kk)
      pf[kk] = *(const bf16x8*)&Pw[l16*72 + kk*32 + quad*8];
    #pragma unroll
    for (int nt = 0; nt < 8; ++nt){
      int row = nt*16 + l16;
      bf16x8 wf[2];
      #pragma unroll
      for (int kk = 0; kk < 2; ++kk)
        wf[kk] = *(const bf16x8*)&SM[16384 + buf*8192 + (row*8 + ((kk*4 + quad) ^ (l16 & 7)))*8];
      #pragma unroll
      for (int kk = 0; kk < 2; ++kk)
        O[nt] = __builtin_amdgcn_mfma_f32_16x16x32_bf16(pf[kk], wf[kk], O[nt], 0, 0, 0);
    }

    if (c + 1 < 32){
      asm volatile("s_waitcnt vmcnt(0)" ::: "memory");
      __syncthreads();
    }
  }

  #pragma unroll
  for (int rr = 0; rr < 4; ++rr){
    int row = m0 + wave*16 + quad*4 + rr;
    float vs[8], sum = 0.f;
    #pragma unroll
    for (int nt = 0; nt < 8; ++nt){
      int col = nt*16 + l16;
      float v = O[nt][rr] + b2[col] + res[nt][rr];
      vs[nt] = v; sum += v;
    }
    sum += __shfl_xor(sum, 1); sum += __shfl_xor(sum, 2);
    sum += __shfl_xor(sum, 4); sum += __shfl_xor(sum, 8);
    float mean = sum * (1.f/DD);
    float sq = 0.f;
    #pragma unroll
    for (int nt = 0; nt < 8; ++nt){ float d = vs[nt] - mean; sq += d*d; }
    sq += __shfl_xor(sq, 1); sq += __shfl_xor(sq, 2);
    sq += __shfl_xor(sq, 4); sq += __shfl_xor(sq, 8);
    float rs = rsqrtf(sq * (1.f/DD) + 1e-5f);
    #pragma unroll
    for (int nt = 0; nt < 8; ++nt){
      int col = nt*16 + l16;
      float o = (vs[nt] - mean)*rs*g2[col] + beta2[col];
      cur[(size_t)row*DD + col]  = o;
      curb[(size_t)row*DD + col] = f2bf(o);
    }
  }
}

// ---------------- final masked mean, two-stage ----------------
__global__ __launch_bounds__(128) void reduce1_kernel(
    const float* __restrict__ cur, const float* __restrict__ mask,
    float* __restrict__ partial, float* __restrict__ cnt)
{
  int b = blockIdx.x, c = blockIdx.y, t = threadIdx.x;
  float acc = 0.f, cn = 0.f;
  for (int s = c*128; s < c*128 + 128; ++s){
    float mk = mask[b*NPER + s];
    acc += cur[(size_t)(b*NPER + s)*DD + t] * mk;
    cn += mk;
  }
  partial[(size_t)(b*8 + c)*DD + t] = acc;
  if (t == 0) cnt[b*8 + c] = cn;
}
__global__ __launch_bounds__(128) void reduce2_kernel(
    const float* __restrict__ partial, const float* __restrict__ cnt,
    const int* __restrict__ flag, void* __restrict__ out)
{
  int b = blockIdx.x, t = threadIdx.x;
  float acc = 0.f, cn = 0.f;
  #pragma unroll
  for (int c = 0; c < 8; ++c){
    acc += partial[(size_t)(b*8 + c)*DD + t];
    cn  += cnt[b*8 + c];
  }
  float val = acc / cn;
  if (*flag) ((u16*)out)[b*DD + t] = f2bf(val);
  else       ((float*)out)[b*DD + t] = val;
}

// ---------------- host ----------------
extern "C" void kernel_launch(void* const* d_in, const int* in_sizes, int n_in,
                              void* d_out, int out_size, void* d_ws, size_t ws_size,
                              hipStream_t stream)
{
  (void)in_sizes; (void)n_in; (void)out_size; (void)ws_size;
  char* ws = (char*)d_ws;
  int*   flag   = (int*)(ws + OFF_FLAG);
  int*   starts = (int*)(ws + OFF_STARTS);
  float* BIN  = (float*)(ws + OFF_BIN);
  float* BQKV = (float*)(ws + OFF_BQKV);
  float* BO   = (float*)(ws + OFF_BO);
  float* B1   = (float*)(ws + OFF_B1);
  float* B2   = (float*)(ws + OFF_B2);
  float* LN1G = (float*)(ws + OFF_LN1G);
  float* LN1B = (float*)(ws + OFF_LN1B);
  float* LN2G = (float*)(ws + OFF_LN2G);
  float* LN2B = (float*)(ws + OFF_LN2B);
  u16* WINB  = (u16*)(ws + OFF_WINB);
  u16* WQKVB = (u16*)(ws + OFF_WQKVB);
  u16* WOB   = (u16*)(ws + OFF_WOB);
  u16* W1B   = (u16*)(ws + OFF_W1B);
  u16* W2B   = (u16*)(ws + OFF_W2B);
  float* CUR = (float*)(ws + OFF_CUR);
  u16* CURB  = (u16*)(ws + OFF_CURB);
  u16* QH    = (u16*)(ws + OFF_QKVB);
  u16* KT    = (u16*)(ws + OFF_QKVB + (size_t)4194304*2);
  u16* ATTNOB= (u16*)(ws + OFF_ATTNOB);
  float* MASK= (float*)(ws + OFF_MASK);
  u16* VTB   = (u16*)(ws + OFF_VT);
  float* RED = (float*)(ws + OFF_RED);
  float* CNT = (float*)(ws + OFF_CNT);

  prep_kernel<<<1, 256, 0, stream>>>((const unsigned*)d_in[0], (const int*)d_in[1],
                                     flag, starts);

  ConvArgs ca;
  ca.s[0]  = { d_in[2],  WINB,  DD*INDIM,   1 };
  ca.s[1]  = { d_in[4],  WQKVB, LL*3*DD*DD, 1 };
  ca.s[2]  = { d_in[6],  WOB,   LL*DD*DD,   1 };
  ca.s[3]  = { d_in[8],  W1B,   LL*DFF*DD,  1 };
  ca.s[4]  = { d_in[10], W2B,   LL*DD*DFF,  1 };
  ca.s[5]  = { d_in[3],  BIN,   DD,         0 };
  ca.s[6]  = { d_in[5],  BQKV,  LL*3*DD,    0 };
  ca.s[7]  = { d_in[7],  BO,    LL*DD,      0 };
  ca.s[8]  = { d_in[9],  B1,    LL*DFF,     0 };
  ca.s[9]  = { d_in[11], B2,    LL*DD,      0 };
  ca.s[10] = { d_in[12], LN1G,  LL*DD,      0 };
  ca.s[11] = { d_in[13], LN1B,  LL*DD,      0 };
  ca.s[12] = { d_in[14], LN2G,  LL*DD,      0 };
  ca.s[13] = { d_in[15], LN2B,  LL*DD,      0 };
  int nblk = 0;
  for (int i = 0; i < 14; ++i) nblk += (ca.s[i].n + 1023) >> 10;
  convall_kernel<<<nblk, 256, 0, stream>>>(ca, flag);

  inproj_kernel<<<NTOT/64, 256, 0, stream>>>(
      d_in[0], WINB, BIN, (const int*)d_in[1], starts, flag, CUR, CURB, MASK);

  for (int l = 0; l < LL; ++l){
    wgemm2_kernel<<<dim3(NTOT/128, 3), 256, 0, stream>>>(
        CURB, WQKVB + (size_t)l*3*DD*DD, BQKV + l*3*DD, QH, KT, VTB);
    fattn_kernel<<<dim3(NPER/128, HH, BB), 256, 0, stream>>>(QH, KT, VTB, ATTNOB);
    ffn_kernel<<<dim3(NTOT/64), 256, 0, stream>>>(
        ATTNOB, WOB + (size_t)l*DD*DD, BO + l*DD, LN1G + l*DD, LN1B + l*DD,
        W1B + (size_t)l*DFF*DD, W2B + (size_t)l*DD*DFF,
        B1 + l*DFF, B2 + l*DD, LN2G + l*DD, LN2B + l*DD, CUR, CURB);
  }

  reduce1_kernel<<<dim3(BB, 8), 128, 0, stream>>>(CUR, MASK, RED, CNT);
  reduce2_kernel<<<BB, 128, 0, stream>>>(RED, CNT, flag, d_out);
}